// Round 1
// baseline (75.492 us; speedup 1.0000x reference)
//
#include <hip/hip_runtime.h>
#include <math.h>

// Problem constants (fixed by the reference):
//   B=16384 rows, x has 256 cols (128 cont + 128 cat), NG=NC=1024, K=32
//   out[b, 0:1024]    = -0.5*z^2 - log(std) - 0.5*log(2pi),  z=(x[b,gsc[g]]-mean[g])/std[g]
//   out[b, 1024:2048] = cat_logp[c, (int)x[b, csc[c]]]
// All inputs f32 except scopes (int32). Output f32.

#define HALF_LOG_2PI 0.91893853320467274178f

constexpr int BROWS   = 16384;
constexpr int FX      = 256;    // x columns
constexpr int NG      = 1024;
constexpr int NC      = 1024;
constexpr int KCAT    = 32;
constexpr int OUTW    = NG + NC;   // 2048
constexpr int ROWS_PB = 8;         // rows per block
constexpr int NTHR    = 256;

__global__ __launch_bounds__(NTHR) void leaves_kernel(
    const float* __restrict__ x,       // [B, 256]
    const float* __restrict__ gmean,   // [1024]
    const float* __restrict__ gstd,    // [1024]
    const float* __restrict__ clogp,   // [1024, 32]
    const int*   __restrict__ gsc,     // [1024] in [0,128)
    const int*   __restrict__ csc,     // [1024] in [128,256)
    float*       __restrict__ out)     // [B, 2048]
{
    __shared__ float xrow[ROWS_PB * FX];   // 8 KB: 8 staged rows

    const int t = threadIdx.x;
    const long long b0 = (long long)blockIdx.x * ROWS_PB;

    // ---- stage 8 rows (2048 floats) coalesced as float4 ----
    const float4* xsrc = (const float4*)(x + b0 * FX);
    float4*       xdst = (float4*)xrow;
    xdst[t]        = xsrc[t];
    xdst[t + NTHR] = xsrc[t + NTHR];

    // ---- per-thread tables (outputs 4t..4t+3 of each half) ----
    const int4   g4 = ((const int4*)gsc)[t];
    const int4   c4 = ((const int4*)csc)[t];
    const float4 mu = ((const float4*)gmean)[t];
    const float4 sd = ((const float4*)gstd)[t];

    float4 is, ct;
    is.x = 1.0f / sd.x;  ct.x = -logf(sd.x) - HALF_LOG_2PI;
    is.y = 1.0f / sd.y;  ct.y = -logf(sd.y) - HALF_LOG_2PI;
    is.z = 1.0f / sd.z;  ct.z = -logf(sd.z) - HALF_LOG_2PI;
    is.w = 1.0f / sd.w;  ct.w = -logf(sd.w) - HALF_LOG_2PI;

    __syncthreads();

    float* orow = out + b0 * OUTW;
    const int cbase = t * 4 * KCAT;   // (4t+k)*32 = cbase + k*32

    #pragma unroll
    for (int r = 0; r < ROWS_PB; ++r) {
        const float* xr = xrow + r * FX;

        // Gaussian half
        float4 gres;
        { float z = (xr[g4.x] - mu.x) * is.x; gres.x = fmaf(-0.5f * z, z, ct.x); }
        { float z = (xr[g4.y] - mu.y) * is.y; gres.y = fmaf(-0.5f * z, z, ct.y); }
        { float z = (xr[g4.z] - mu.z) * is.z; gres.z = fmaf(-0.5f * z, z, ct.z); }
        { float z = (xr[g4.w] - mu.w) * is.w; gres.w = fmaf(-0.5f * z, z, ct.w); }

        // Categorical half (dependent gather into 128KB table)
        float4 cres;
        cres.x = clogp[cbase + 0 * KCAT + (int)xr[c4.x]];
        cres.y = clogp[cbase + 1 * KCAT + (int)xr[c4.y]];
        cres.z = clogp[cbase + 2 * KCAT + (int)xr[c4.z]];
        cres.w = clogp[cbase + 3 * KCAT + (int)xr[c4.w]];

        float4* op = (float4*)(orow + (long long)r * OUTW);
        op[t]        = gres;   // out[b0+r, 4t .. 4t+3]
        op[NTHR + t] = cres;   // out[b0+r, 1024 + 4t .. ]
    }
}

extern "C" void kernel_launch(void* const* d_in, const int* in_sizes, int n_in,
                              void* d_out, int out_size, void* d_ws, size_t ws_size,
                              hipStream_t stream) {
    const float* x     = (const float*)d_in[0];
    const float* gmean = (const float*)d_in[1];
    const float* gstd  = (const float*)d_in[2];
    const float* clogp = (const float*)d_in[3];
    const int*   gsc   = (const int*)d_in[4];
    const int*   csc   = (const int*)d_in[5];
    float*       out   = (float*)d_out;

    dim3 grid(BROWS / ROWS_PB);   // 2048 blocks
    dim3 block(NTHR);
    leaves_kernel<<<grid, block, 0, stream>>>(x, gmean, gstd, clogp, gsc, csc, out);
}

// Round 2
// 65.731 us; speedup vs baseline: 1.1485x; 1.1485x over previous
//
#include <hip/hip_runtime.h>
#include <math.h>

// out[b, 0:1024]    = -0.5*z^2 - log(std) - 0.5*log(2pi),  z=(x[b,gsc[g]]-mean[g])/std[g]
// out[b, 1024:2048] = cat_logp[c, (int)x[b, csc[c]]]
// B=16384, x:[B,256] f32, NG=NC=1024, K=32. Latency-bound kernel -> maximize MLP:
// issue all 32 cat gathers per thread up front, do Gaussian work under them.

#define HALF_LOG_2PI 0.91893853320467274178f

constexpr int BROWS   = 16384;
constexpr int FX      = 256;
constexpr int NG      = 1024;
constexpr int NC      = 1024;
constexpr int KCAT    = 32;
constexpr int OUTW    = NG + NC;   // 2048
constexpr int ROWS_PB = 8;
constexpr int NTHR    = 256;

__global__ __launch_bounds__(NTHR) void leaves_kernel(
    const float* __restrict__ x,       // [B, 256]
    const float* __restrict__ gmean,   // [1024]
    const float* __restrict__ gstd,    // [1024]
    const float* __restrict__ clogp,   // [1024, 32]
    const int*   __restrict__ gsc,     // [1024] in [0,128)
    const int*   __restrict__ csc,     // [1024] in [128,256)
    float*       __restrict__ out)     // [B, 2048]
{
    __shared__ float xrow[ROWS_PB * FX];   // 8 KB

    const int t = threadIdx.x;
    const long long b0 = (long long)blockIdx.x * ROWS_PB;

    // stage 8 x-rows coalesced
    const float4* xsrc = (const float4*)(x + b0 * FX);
    float4*       xdst = (float4*)xrow;
    xdst[t]        = xsrc[t];
    xdst[t + NTHR] = xsrc[t + NTHR];

    // per-thread tables (thread owns outputs 4t..4t+3 of each half)
    const int4   g4 = ((const int4*)gsc)[t];
    const int4   c4 = ((const int4*)csc)[t];
    const float4 mu = ((const float4*)gmean)[t];
    const float4 sd = ((const float4*)gstd)[t];

    float4 is, ct;
    is.x = 1.0f / sd.x;  ct.x = -logf(sd.x) - HALF_LOG_2PI;
    is.y = 1.0f / sd.y;  ct.y = -logf(sd.y) - HALF_LOG_2PI;
    is.z = 1.0f / sd.z;  ct.z = -logf(sd.z) - HALF_LOG_2PI;
    is.w = 1.0f / sd.w;  ct.w = -logf(sd.w) - HALF_LOG_2PI;

    __syncthreads();

    const int cbase = t * 4 * KCAT;

    // ---- Phase A: issue ALL 32 cat gathers (32 independent loads in flight) ----
    float cres[ROWS_PB][4];
    #pragma unroll
    for (int r = 0; r < ROWS_PB; ++r) {
        const float* xr = xrow + r * FX;
        cres[r][0] = clogp[cbase + 0 * KCAT + (int)xr[c4.x]];
        cres[r][1] = clogp[cbase + 1 * KCAT + (int)xr[c4.y]];
        cres[r][2] = clogp[cbase + 2 * KCAT + (int)xr[c4.z]];
        cres[r][3] = clogp[cbase + 3 * KCAT + (int)xr[c4.w]];
    }

    // ---- Phase B: Gaussian half (LDS + VALU) under the gather latency; store it ----
    #pragma unroll
    for (int r = 0; r < ROWS_PB; ++r) {
        const float* xr = xrow + r * FX;
        float4 gres;
        { float z = (xr[g4.x] - mu.x) * is.x; gres.x = fmaf(-0.5f * z, z, ct.x); }
        { float z = (xr[g4.y] - mu.y) * is.y; gres.y = fmaf(-0.5f * z, z, ct.y); }
        { float z = (xr[g4.z] - mu.z) * is.z; gres.z = fmaf(-0.5f * z, z, ct.z); }
        { float z = (xr[g4.w] - mu.w) * is.w; gres.w = fmaf(-0.5f * z, z, ct.w); }
        ((float4*)(out + (b0 + r) * OUTW))[t] = gres;
    }

    // ---- Phase C: store cat half as results arrive ----
    #pragma unroll
    for (int r = 0; r < ROWS_PB; ++r) {
        float4 cv;
        cv.x = cres[r][0]; cv.y = cres[r][1]; cv.z = cres[r][2]; cv.w = cres[r][3];
        ((float4*)(out + (b0 + r) * OUTW + NG))[t] = cv;
    }
}

extern "C" void kernel_launch(void* const* d_in, const int* in_sizes, int n_in,
                              void* d_out, int out_size, void* d_ws, size_t ws_size,
                              hipStream_t stream) {
    const float* x     = (const float*)d_in[0];
    const float* gmean = (const float*)d_in[1];
    const float* gstd  = (const float*)d_in[2];
    const float* clogp = (const float*)d_in[3];
    const int*   gsc   = (const int*)d_in[4];
    const int*   csc   = (const int*)d_in[5];
    float*       out   = (float*)d_out;

    leaves_kernel<<<dim3(BROWS / ROWS_PB), dim3(NTHR), 0, stream>>>(
        x, gmean, gstd, clogp, gsc, csc, out);
}

// Round 3
// 30.539 us; speedup vs baseline: 2.4720x; 2.1523x over previous
//
#include <hip/hip_runtime.h>
#include <math.h>

// out[b, 0:1024]    = -0.5*z^2 - log(std) - 0.5*log(2pi),  z=(x[b,gsc[g]]-mean[g])/std[g]
// out[b, 1024:2048] = cat_logp[c, (int)x[b, csc[c]]]
// B=16384, x:[B,256] f32, NG=NC=1024, K=32.
//
// Design B: gather-transposed. Within a wave, lanes = rows (l&15) so one cat
// gather instruction covers 4 consecutive c's (l>>4) x 128B table blocks
// = <=8 cache lines/instr (vs 64 in the lane=c mapping). Cat results go
// through a padded LDS tile and flush with coalesced 256B-segment stores.

#define HALF_LOG_2PI 0.91893853320467274178f

constexpr int BROWS   = 16384;
constexpr int FX      = 256;
constexpr int NG      = 1024;
constexpr int NC      = 1024;
constexpr int KCAT    = 32;
constexpr int OUTW    = NG + NC;   // 2048
constexpr int ROWS_PB = 16;
constexpr int NTHR    = 256;
constexpr int XPITCH  = FX + 1;    // 257: bank = (row + col) % 32 -> spread
constexpr int CCH     = 128;       // cat cols per chunk
constexpr int NCHUNK  = NC / CCH;  // 8
constexpr int CPITCH  = CCH + 4;   // 132: write bank = (4*row + off) % 32 -> 2-way max

__global__ __launch_bounds__(NTHR) void leaves_kernel(
    const float* __restrict__ x,       // [B, 256]
    const float* __restrict__ gmean,   // [1024]
    const float* __restrict__ gstd,    // [1024]
    const float* __restrict__ clogp,   // [1024, 32]
    const int*   __restrict__ gsc,     // [1024] in [0,128)
    const int*   __restrict__ csc,     // [1024] in [128,256)
    float*       __restrict__ out)     // [B, 2048]
{
    __shared__ float xs[ROWS_PB * XPITCH];   // 16448 B
    __shared__ float cts[ROWS_PB * CPITCH];  //  8448 B

    const int t = threadIdx.x;
    const long long b0 = (long long)blockIdx.x * ROWS_PB;

    // ---- stage 16 x-rows: thread t loads row t>>4, cols (t&15)*16..+15 ----
    {
        const int r  = t >> 4;
        const int c0 = (t & 15) * 16;
        const float* src = x + (b0 + r) * FX + c0;
        float*       dst = xs + r * XPITCH + c0;
        #pragma unroll
        for (int q = 0; q < 4; ++q) {
            float4 v = ((const float4*)src)[q];
            dst[q * 4 + 0] = v.x; dst[q * 4 + 1] = v.y;
            dst[q * 4 + 2] = v.z; dst[q * 4 + 3] = v.w;
        }
    }

    // ---- per-thread gaussian tables (thread owns g-cols 4t..4t+3) ----
    const int4   g4 = ((const int4*)gsc)[t];
    const float4 mu = ((const float4*)gmean)[t];
    const float4 sd = ((const float4*)gstd)[t];
    float4 is, cc;
    is.x = 1.0f / sd.x;  cc.x = -logf(sd.x) - HALF_LOG_2PI;
    is.y = 1.0f / sd.y;  cc.y = -logf(sd.y) - HALF_LOG_2PI;
    is.z = 1.0f / sd.z;  cc.z = -logf(sd.z) - HALF_LOG_2PI;
    is.w = 1.0f / sd.w;  cc.w = -logf(sd.w) - HALF_LOG_2PI;

    __syncthreads();

    // ---- Gaussian half: 16 rows, coalesced 1KB wave stores ----
    #pragma unroll
    for (int r = 0; r < ROWS_PB; ++r) {
        const float* xr = xs + r * XPITCH;
        float4 gres;
        { float z = (xr[g4.x] - mu.x) * is.x; gres.x = fmaf(-0.5f * z, z, cc.x); }
        { float z = (xr[g4.y] - mu.y) * is.y; gres.y = fmaf(-0.5f * z, z, cc.y); }
        { float z = (xr[g4.z] - mu.z) * is.z; gres.z = fmaf(-0.5f * z, z, cc.z); }
        { float z = (xr[g4.w] - mu.w) * is.w; gres.w = fmaf(-0.5f * z, z, cc.w); }
        ((float4*)(out + (b0 + r) * OUTW))[t] = gres;
    }

    // ---- Cat half: lanes = rows; 4 consecutive c per wave-instr ----
    const int w   = t >> 6;        // wave 0..3
    const int l   = t & 63;
    const int row = l & 15;        // lane's row
    const int co  = l >> 4;        // 0..3: c sub-offset
    const float* xrp = xs + row * XPITCH;

    const int wr = t >> 4;          // write-phase row
    const int wo = (t & 15) * 4;    // write-phase col offset

    for (int chunk = 0; chunk < NCHUNK; ++chunk) {
        const int cb = chunk * CCH + w * 32 + co;   // this thread's c = cb + 4j

        int sc[8];
        #pragma unroll
        for (int j = 0; j < 8; ++j) sc[j] = csc[cb + j * 4];

        int ix[8];
        #pragma unroll
        for (int j = 0; j < 8; ++j) ix[j] = (int)xrp[sc[j]];

        float v[8];
        #pragma unroll
        for (int j = 0; j < 8; ++j) v[j] = clogp[(cb + j * 4) * KCAT + ix[j]];

        #pragma unroll
        for (int j = 0; j < 8; ++j)
            cts[row * CPITCH + w * 32 + j * 4 + co] = v[j];

        __syncthreads();

        // flush: thread t writes row wr, floats wo..wo+3 and wo+64..wo+67
        {
            float4 a = *(const float4*)(cts + wr * CPITCH + wo);
            float4 b = *(const float4*)(cts + wr * CPITCH + wo + 64);
            float* dst = out + (b0 + wr) * OUTW + NG + chunk * CCH;
            *(float4*)(dst + wo)      = a;
            *(float4*)(dst + wo + 64) = b;
        }
        __syncthreads();
    }
}

extern "C" void kernel_launch(void* const* d_in, const int* in_sizes, int n_in,
                              void* d_out, int out_size, void* d_ws, size_t ws_size,
                              hipStream_t stream) {
    const float* x     = (const float*)d_in[0];
    const float* gmean = (const float*)d_in[1];
    const float* gstd  = (const float*)d_in[2];
    const float* clogp = (const float*)d_in[3];
    const int*   gsc   = (const int*)d_in[4];
    const int*   csc   = (const int*)d_in[5];
    float*       out   = (float*)d_out;

    leaves_kernel<<<dim3(BROWS / ROWS_PB), dim3(NTHR), 0, stream>>>(
        x, gmean, gstd, clogp, gsc, csc, out);
}